// Round 4
// baseline (276.244 us; speedup 1.0000x reference)
//
#include <hip/hip_runtime.h>
#include <cstdint>
#include <cstddef>

typedef unsigned short u16;
typedef __bf16 bf16x8 __attribute__((ext_vector_type(8)));
typedef float f32x4 __attribute__((ext_vector_type(4)));
typedef u16 u16x4 __attribute__((ext_vector_type(4)));

#define DMODEL 1024
#define DINNER 2048
#define NBATCH 2
#define LSEQ   2048
#define NTOK   4096   // NBATCH * LSEQ
#define NSTATE 16
#define NCH    32     // scan chunks
#define TCH    64     // timesteps per chunk (NCH*TCH == LSEQ)

__device__ __forceinline__ u16 f2b(float f) {
  union { float f; unsigned u; } a; a.f = f;
  unsigned r = a.u + 0x7fffu + ((a.u >> 16) & 1u);
  return (u16)(r >> 16);
}
__device__ __forceinline__ float b2f(u16 h) {
  union { unsigned u; float f; } a; a.u = ((unsigned)h) << 16;
  return a.f;
}

__device__ __forceinline__ void gload_lds16(const u16* g, __bf16* l) {
  __builtin_amdgcn_global_load_lds(
      (const __attribute__((address_space(1))) unsigned int*)g,
      (__attribute__((address_space(3))) unsigned int*)l, 16, 0, 0);
}

// ---------------- transpose + f32->bf16 convert: dst[c*R + r] = src[r*C + c]
__global__ __launch_bounds__(256)
void transpose_cvt(const float* __restrict__ src, u16* __restrict__ dst, int R, int C) {
  __shared__ float tile[32][33];
  int c0 = blockIdx.x * 32, r0 = blockIdx.y * 32;
  int x = threadIdx.x, y = threadIdx.y;            // blockDim (32,8)
  #pragma unroll
  for (int yy = y; yy < 32; yy += 8)
    if (r0 + yy < R && c0 + x < C) tile[yy][x] = src[(size_t)(r0 + yy) * C + c0 + x];
  __syncthreads();
  #pragma unroll
  for (int yy = y; yy < 32; yy += 8)
    if (c0 + yy < C && r0 + x < R) dst[(size_t)(c0 + yy) * R + r0 + x] = f2b(tile[x][yy]);
}

// ---------------- RMSNorm -> bf16 (one block per row of 1024)
__global__ __launch_bounds__(256)
void rmsnorm_k(const float* __restrict__ x, const float* __restrict__ scale, u16* __restrict__ xn) {
  int row = blockIdx.x;
  const float4* xp = (const float4*)(x + (size_t)row * DMODEL);
  float4 v = xp[threadIdx.x];
  float ss = v.x * v.x + v.y * v.y + v.z * v.z + v.w * v.w;
  #pragma unroll
  for (int o = 32; o; o >>= 1) ss += __shfl_down(ss, o);
  __shared__ float wsum[4];
  if ((threadIdx.x & 63) == 0) wsum[threadIdx.x >> 6] = ss;
  __syncthreads();
  float tot = wsum[0] + wsum[1] + wsum[2] + wsum[3];
  float r = rsqrtf(tot * (1.0f / DMODEL) + 1e-6f);
  float4 sc = ((const float4*)scale)[threadIdx.x];
  u16x4 o4;
  o4[0] = f2b(v.x * r * sc.x); o4[1] = f2b(v.y * r * sc.y);
  o4[2] = f2b(v.z * r * sc.z); o4[3] = f2b(v.w * r * sc.w);
  *(u16x4*)(xn + (size_t)row * DMODEL + threadIdx.x * 4) = o4;
}

// ======== double-buffered counted-vmcnt MFMA GEMM with XCD-rect L2 blocking ========
// out[M][N] = A[M][K]*Bt[N][K]. Grid must be 8*RM*RN blocks; XCD x runs an RMxRN
// rectangle of tiles -> row/col panels L2-resident, L3 re-fetch cut ~5x.
// EPI: 0 = +bias -> bf16, 3 = +bias+residual -> f32
template <int BM, int BN, int NWM, int NWN, int EPI>
__global__ __launch_bounds__(NWM * NWN * 64, 1)
void gemm_db(const u16* __restrict__ A, const u16* __restrict__ Bt,
             const float* __restrict__ bias, const float* __restrict__ res,
             void* __restrict__ outv, int M, int N, int K, int RM, int RN) {
  constexpr int NTHR = NWM * NWN * 64;
  constexpr int WMW = BM / NWM;
  constexpr int WNW = BN / NWN;
  constexpr int MF = WMW / 16;
  constexpr int NF = WNW / 16;
  constexpr int LPT = (BM + BN) * 8 / NTHR;   // global_load_lds per thread per tile
  __shared__ __bf16 lds[2][(BM + BN) * 64];
  const int tid = threadIdx.x;
  const int lane = tid & 63;
  const int wave = tid >> 6;
  const int wr = wave / NWN, wc = wave % NWN;

  const int GM = M / BM;
  const int bid = blockIdx.x;
  const int xcd = bid & 7;
  const int l = bid >> 3;
  const int rgm = GM / RM;
  const int rr = xcd % rgm, rc = xcd / rgm;
  const size_t m0 = (size_t)(rr * RM + (l % RM)) * BM;
  const size_t n0 = (size_t)(rc * RN + (l / RM)) * BN;
  const int NT = K >> 6;

#define STAGE_DB(bufi, k0)                                                     \
  { _Pragma("unroll")                                                          \
    for (int ss = 0; ss < BM * 8 / NTHR; ss++) {                               \
      int g = tid + ss * NTHR;                                                 \
      int row = g >> 3;                                                        \
      int kk = ((g & 7) * 8) ^ ((row & 7) << 3);                               \
      gload_lds16(A + (m0 + row) * K + (k0) + kk, &lds[bufi][g * 8]);          \
    }                                                                          \
    _Pragma("unroll")                                                          \
    for (int ss = 0; ss < BN * 8 / NTHR; ss++) {                               \
      int g = tid + ss * NTHR;                                                 \
      int row = g >> 3;                                                        \
      int kk = ((g & 7) * 8) ^ ((row & 7) << 3);                               \
      gload_lds16(Bt + (n0 + row) * K + (k0) + kk,                             \
                  &lds[bufi][BM * 64 + g * 8]);                                \
    } }

  f32x4 acc[MF][NF] = {};
  STAGE_DB(0, 0)
  STAGE_DB(1, 64)

  const int rsw = (lane & 7) << 3;
  const int arow0 = wr * WMW + (lane & 15);
  const int brow0 = wc * WNW + (lane & 15);
  const int kgrp = (lane >> 4) * 8;

  for (int t = 0; t < NT; t++) {
    const int cur = t & 1;
    if (t == NT - 1) asm volatile("s_waitcnt vmcnt(0)" ::: "memory");
    else             asm volatile("s_waitcnt vmcnt(%0)" :: "n"(LPT) : "memory");
    __builtin_amdgcn_s_barrier();
    asm volatile("" ::: "memory");
    const __bf16* As_ = &lds[cur][0];
    const __bf16* Bs_ = &lds[cur][BM * 64];
    #pragma unroll
    for (int qr = 0; qr < MF / 4; qr++) {
      #pragma unroll
      for (int qc = 0; qc < NF / 2; qc++) {
        bf16x8 af[2][4], bfv[2][2];
        #pragma unroll
        for (int ks = 0; ks < 2; ks++) {
          const int kk = (ks * 32 + kgrp) ^ rsw;
          #pragma unroll
          for (int i = 0; i < 4; i++)
            af[ks][i] = *(const bf16x8*)(As_ + (size_t)(arow0 + (qr * 4 + i) * 16) * 64 + kk);
          #pragma unroll
          for (int j = 0; j < 2; j++)
            bfv[ks][j] = *(const bf16x8*)(Bs_ + (size_t)(brow0 + (qc * 2 + j) * 16) * 64 + kk);
        }
        __builtin_amdgcn_s_setprio(1);
        #pragma unroll
        for (int ks = 0; ks < 2; ks++)
          #pragma unroll
          for (int i = 0; i < 4; i++)
            #pragma unroll
            for (int j = 0; j < 2; j++)
              acc[qr * 4 + i][qc * 2 + j] = __builtin_amdgcn_mfma_f32_16x16x32_bf16(
                  af[ks][i], bfv[ks][j], acc[qr * 4 + i][qc * 2 + j], 0, 0, 0);
        __builtin_amdgcn_s_setprio(0);
        __builtin_amdgcn_sched_barrier(0);
      }
    }
    __builtin_amdgcn_s_barrier();
    asm volatile("" ::: "memory");
    if (t + 2 < NT) { STAGE_DB(cur, (t + 2) * 64) }
  }

  const int cr = (lane >> 4) << 2;
  const int cc = lane & 15;
  #pragma unroll
  for (int fr = 0; fr < MF; fr++) {
    #pragma unroll
    for (int fc = 0; fc < NF; fc++) {
      const size_t col = n0 + wc * WNW + fc * 16 + cc;
      const float bv = bias[col];
      #pragma unroll
      for (int r = 0; r < 4; r++) {
        const size_t row = m0 + wr * WMW + fr * 16 + cr + r;
        if constexpr (EPI == 0) {
          ((u16*)outv)[row * N + col] = f2b(acc[fr][fc][r] + bv);
        } else {
          ((float*)outv)[row * N + col] = acc[fr][fc][r] + bv + res[row * N + col];
        }
      }
    }
  }
#undef STAGE_DB
}

// ---------------- padded reg-staged 2-phase GEMM for small shapes
// EPI: 1 = plain -> f32 partial (blockIdx.z offset), 2 = softplus+clip(+bias) -> bf16
template <int EPI, int BN>
__global__ __launch_bounds__(256)
void gemm_bt(const u16* __restrict__ A, const u16* __restrict__ Bt,
             const float* __restrict__ bias, const float* __restrict__ res,
             void* __restrict__ outv, int M, int N, int K, int ksplit) {
  constexpr int WN = BN / 2;
  constexpr int JN = WN / 16;
  __shared__ __bf16 As[128][72];
  __shared__ __bf16 Bs[BN][72];
  const int tid = threadIdx.x;
  const int m0 = blockIdx.y * 128;
  const int n0 = blockIdx.x * BN;
  const int wave = tid >> 6, lane = tid & 63;
  const int wm = (wave >> 1) * 64, wn = (wave & 1) * WN;
  const int sr = tid >> 3;
  const int sc = (tid & 7) * 8;
  const int kbeg = blockIdx.z * ksplit, kend = kbeg + ksplit;
  f32x4 acc[4][JN] = {};
  for (int k0 = kbeg; k0 < kend; k0 += 64) {
    __syncthreads();
    #pragma unroll
    for (int r = 0; r < 128; r += 32)
      *(bf16x8*)&As[sr + r][sc] = *(const bf16x8*)(A + (size_t)(m0 + sr + r) * K + k0 + sc);
    #pragma unroll
    for (int r = 0; r < BN; r += 32)
      *(bf16x8*)&Bs[sr + r][sc] = *(const bf16x8*)(Bt + (size_t)(n0 + sr + r) * K + k0 + sc);
    __syncthreads();
    #pragma unroll
    for (int ks = 0; ks < 64; ks += 32) {
      const int kr = ks + ((lane >> 4) << 3);
      bf16x8 af[4], bfr[JN];
      #pragma unroll
      for (int i = 0; i < 4; i++) af[i]  = *(const bf16x8*)&As[wm + (lane & 15) + i * 16][kr];
      #pragma unroll
      for (int j = 0; j < JN; j++) bfr[j] = *(const bf16x8*)&Bs[wn + (lane & 15) + j * 16][kr];
      #pragma unroll
      for (int i = 0; i < 4; i++)
        #pragma unroll
        for (int j = 0; j < JN; j++)
          acc[i][j] = __builtin_amdgcn_mfma_f32_16x16x32_bf16(af[i], bfr[j], acc[i][j], 0, 0, 0);
    }
  }
  const int cr = (lane >> 4) << 2;
  const int cc = lane & 15;
  #pragma unroll
  for (int i = 0; i < 4; i++) {
    #pragma unroll
    for (int j = 0; j < JN; j++) {
      const int col = n0 + wn + j * 16 + cc;
      #pragma unroll
      for (int r = 0; r < 4; r++) {
        const int row = m0 + wm + i * 16 + cr + r;
        float v = acc[i][j][r];
        if constexpr (EPI == 1) {
          ((float*)outv)[(size_t)blockIdx.z * M * N + (size_t)row * N + col] = v;
        } else {
          v += bias[col];
          v = (v > 20.0f) ? v : log1pf(__expf(v));
          v = fminf(fmaxf(v, 0.001f), 0.1f);
          ((u16*)outv)[(size_t)row * N + col] = f2b(v);
        }
      }
    }
  }
}

// ---------------- causal depthwise conv(4) + bias + SiLU -> bf16 (read-once)
__global__ __launch_bounds__(256)
void conv_silu_seq(const u16* __restrict__ uz, const float* __restrict__ ck,
                   const float* __restrict__ cb, u16* __restrict__ u) {
  int d  = (blockIdx.x & 7) * 256 + threadIdx.x;
  int lc = (blockIdx.x >> 3) & 31;
  int b  = blockIdx.x >> 8;
  const float w0 = ck[d], w1 = ck[DINNER + d], w2 = ck[2 * DINNER + d], w3 = ck[3 * DINNER + d];
  const float bias = cb[d];
  const int t0 = lc * 64;
  float x0 = 0.f, x1 = 0.f, x2 = 0.f;
  #pragma unroll
  for (int j = -3; j < 0; j++) {
    int t = t0 + j;
    float v = (t >= 0) ? b2f(uz[((size_t)(b * LSEQ + t)) * (2 * DINNER) + d]) : 0.f;
    x0 = x1; x1 = x2; x2 = v;
  }
  for (int i = 0; i < 64; i++) {
    int t = t0 + i;
    float x3 = b2f(uz[((size_t)(b * LSEQ + t)) * (2 * DINNER) + d]);
    float acc = bias + w0 * x0 + w1 * x1 + w2 * x2 + w3 * x3;
    float sv = acc / (1.0f + __expf(-acc));
    u[((size_t)(b * LSEQ + t)) * DINNER + d] = f2b(sv);
    x0 = x1; x1 = x2; x2 = x3;
  }
}

// ---------------- reduce split-K partials + split dtbc
__global__ __launch_bounds__(256)
void prep_dtbc(const float* __restrict__ dtbc, const float* __restrict__ dtin_b,
               const float* __restrict__ bb, const float* __restrict__ cbias,
               u16* __restrict__ dt1, float* __restrict__ Bm, float* __restrict__ Cm) {
  int idx = blockIdx.x * 256 + threadIdx.x;
  if (idx >= NTOK * 96) return;
  int row = idx / 96, col = idx - row * 96;
  float v = 0.f;
  #pragma unroll
  for (int z = 0; z < 8; z++)
    v += dtbc[(size_t)z * NTOK * 128 + (size_t)row * 128 + col];
  if (col < 64)       dt1[(size_t)row * 64 + col] = f2b(v + dtin_b[col]);
  else if (col < 80)  Bm[(size_t)row * NSTATE + col - 64] = tanhf(v + bb[col - 64]);
  else                Cm[(size_t)row * NSTATE + col - 80] = tanhf(v + cbias[col - 80]);
}

__global__ void bias_combine(const float* a, const float* b, float* o) {
  int i = blockIdx.x * 256 + threadIdx.x;
  if (i < DINNER) o[i] = a[i] + b[i];
}

// ======== chunked selective scan, state-split 2 (8 states/lane), B/C in LDS ========
// pass1: per (b,d,chunk) local (P,S). layout chP/chS: [b][ch][d][s]
__global__ __launch_bounds__(256)
void scan_pass1(const u16* __restrict__ dt, const u16* __restrict__ u,
                const float* __restrict__ Bm, const float* __restrict__ alog,
                float* __restrict__ chP, float* __restrict__ chS) {
  __shared__ float Bs[TCH][NSTATE];
  const int bid = blockIdx.x;
  const int dgrp = bid & 15;
  const int ch   = (bid >> 4) & (NCH - 1);
  const int b    = bid >> 9;
  const int lane = threadIdx.x & 63, wave = threadIdx.x >> 6;
  const int d  = dgrp * 128 + wave * 32 + (lane & 31);
  const int sh = (lane >> 5) * 8;
  const int t0 = ch * TCH;
  for (int i = threadIdx.x; i < TCH * NSTATE; i += 256)
    ((float*)Bs)[i] = Bm[((size_t)b * LSEQ + t0) * NSTATE + i];
  __syncthreads();
  float A[8], h[8], P[8];
  #pragma unroll
  for (int s = 0; s < 8; s++) {
    A[s] = -__expf(alog[(size_t)d * NSTATE + sh + s]);
    h[s] = 0.f; P[s] = 1.f;
  }
  for (int i = 0; i < TCH; i++) {
    const size_t tok = (size_t)b * LSEQ + t0 + i;
    float dtv = b2f(dt[tok * DINNER + d]);
    float uv  = b2f(u[tok * DINNER + d]);
    float dtu = dtv * uv;
    #pragma unroll
    for (int s = 0; s < 8; s++) {
      float da = __expf(dtv * A[s]);
      P[s] *= da;
      h[s] = da * h[s] + dtu * Bs[i][sh + s];
    }
  }
  size_t base = (((size_t)b * NCH + ch) * DINNER + d) * NSTATE + sh;
  #pragma unroll
  for (int s = 0; s < 8; s++) { chP[base + s] = P[s]; chS[base + s] = h[s]; }
}

// pass2: stitch chunks; threads cover (d,s) contiguously -> coalesced
__global__ __launch_bounds__(256)
void scan_pass2(const float* __restrict__ chP, const float* __restrict__ chS,
                float* __restrict__ hst) {
  const int b   = blockIdx.x >> 7;                       // 128 blocks per batch
  const int off = (blockIdx.x & 127) * 256 + threadIdx.x; // d*16+s
  float h = 0.f;
  const size_t stride = (size_t)DINNER * NSTATE;
  size_t base = (size_t)b * NCH * stride + off;
  for (int c = 0; c < NCH; c++) {
    size_t a = base + (size_t)c * stride;
    hst[a] = h;
    h = chP[a] * h + chS[a];
  }
}

// pass3: replay + y = (sum h*c + u*d) * silu(z) -> bf16
__global__ __launch_bounds__(256)
void scan_pass3(const u16* __restrict__ dt, const u16* __restrict__ u,
                const float* __restrict__ Bm, const float* __restrict__ Cm,
                const float* __restrict__ alog, const float* __restrict__ dvec,
                const u16* __restrict__ uz, const float* __restrict__ hst,
                u16* __restrict__ y) {
  __shared__ float Bs[TCH][NSTATE];
  __shared__ float Cs[TCH][NSTATE];
  const int bid = blockIdx.x;
  const int dgrp = bid & 15;
  const int ch   = (bid >> 4) & (NCH - 1);
  const int b    = bid >> 9;
  const int lane = threadIdx.x & 63, wave = threadIdx.x >> 6;
  const int d  = dgrp * 128 + wave * 32 + (lane & 31);
  const int sh = (lane >> 5) * 8;
  const int t0 = ch * TCH;
  for (int i = threadIdx.x; i < TCH * NSTATE; i += 256) {
    ((float*)Bs)[i] = Bm[((size_t)b * LSEQ + t0) * NSTATE + i];
    ((float*)Cs)[i] = Cm[((size_t)b * LSEQ + t0) * NSTATE + i];
  }
  __syncthreads();
  float A[8], h[8];
  const size_t hbase = (((size_t)b * NCH + ch) * DINNER + d) * NSTATE + sh;
  #pragma unroll
  for (int s = 0; s < 8; s++) {
    A[s] = -__expf(alog[(size_t)d * NSTATE + sh + s]);
    h[s] = hst[hbase + s];
  }
  const float dval = dvec[d];
  for (int i = 0; i < TCH; i++) {
    const size_t tok = (size_t)b * LSEQ + t0 + i;
    float dtv = b2f(dt[tok * DINNER + d]);
    float uv  = b2f(u[tok * DINNER + d]);
    float dtu = dtv * uv;
    float yv = 0.f;
    #pragma unroll
    for (int s = 0; s < 8; s++) {
      float da = __expf(dtv * A[s]);
      h[s] = da * h[s] + dtu * Bs[i][sh + s];
      yv += h[s] * Cs[i][sh + s];
    }
    yv += __shfl_xor(yv, 32);
    if (sh == 0) {
      yv += uv * dval;
      float z = b2f(uz[tok * (2 * DINNER) + DINNER + d]);
      float g = z / (1.0f + __expf(-z));
      y[tok * DINNER + d] = f2b(yv * g);
    }
  }
}

// ---------------- workspace layout (bytes)
#define WS_XN     ((size_t)0)                  // 4096*1024*2
#define WS_WINT   (WS_XN     + 8388608)        // 4096*1024*2
#define WS_WOUTT  (WS_WINT   + 8388608)        // 1024*2048*2
#define WS_WBC    (WS_WOUTT  + 4194304)        // 128*2048*2
#define WS_WDT2T  (WS_WBC    + 524288)         // 2048*64*2
#define WS_DT1    (WS_WDT2T  + 262144)         // 4096*64*2
#define WS_DTB2   (WS_DT1    + 524288)         // 2048*4
#define WS_BMAT   (WS_DTB2   + 8192)           // 4096*16*4
#define WS_CMAT   (WS_BMAT   + 262144)
#define WS_UZ     (WS_CMAT   + 262144)         // 4096*4096*2 (bf16)
#define WS_U      (WS_UZ     + 33554432)       // 4096*2048*2
#define WS_DTBC   (WS_U      + 16777216)       // 8*4096*128*4 (split-K partials)
#define WS_DT     (WS_DTBC   + 16777216)       // 4096*2048*2 (bf16)
#define WS_CHP    (WS_DT     + 16777216)       // 2*32*2048*16*4
#define WS_CHS    (WS_CHP    + 8388608)
#define WS_HST    (WS_CHS    + 8388608)
#define WS_YBF    (WS_HST    + 8388608)        // 4096*2048*2

extern "C" void kernel_launch(void* const* d_in, const int* in_sizes, int n_in,
                              void* d_out, int out_size, void* d_ws, size_t ws_size,
                              hipStream_t stream) {
  const float* x      = (const float*)d_in[0];
  const float* nscale = (const float*)d_in[1];
  const float* w_in   = (const float*)d_in[2];
  const float* b_in   = (const float*)d_in[3];
  const float* w_out  = (const float*)d_in[4];
  const float* b_out  = (const float*)d_in[5];
  const float* w_dti  = (const float*)d_in[6];
  const float* b_dti  = (const float*)d_in[7];
  const float* w_dto  = (const float*)d_in[8];
  const float* b_dto  = (const float*)d_in[9];
  const float* w_b    = (const float*)d_in[10];
  const float* b_b    = (const float*)d_in[11];
  const float* w_c    = (const float*)d_in[12];
  const float* b_c    = (const float*)d_in[13];
  const float* convk  = (const float*)d_in[14];
  const float* convb  = (const float*)d_in[15];
  const float* alog   = (const float*)d_in[16];
  const float* dvec   = (const float*)d_in[17];
  const float* dtbias = (const float*)d_in[18];
  float* out = (float*)d_out;
  char* ws = (char*)d_ws;

  u16*  XN    = (u16*)(ws + WS_XN);
  u16*  WINT  = (u16*)(ws + WS_WINT);
  u16*  WOUTT = (u16*)(ws + WS_WOUTT);
  u16*  WBC   = (u16*)(ws + WS_WBC);
  u16*  WDT2T = (u16*)(ws + WS_WDT2T);
  u16*  DT1   = (u16*)(ws + WS_DT1);
  float* DTB2 = (float*)(ws + WS_DTB2);
  float* BMAT = (float*)(ws + WS_BMAT);
  float* CMAT = (float*)(ws + WS_CMAT);
  u16*  UZ    = (u16*)(ws + WS_UZ);
  u16*  U     = (u16*)(ws + WS_U);
  float* DTBC = (float*)(ws + WS_DTBC);
  u16*  DT    = (u16*)(ws + WS_DT);
  float* CHP  = (float*)(ws + WS_CHP);
  float* CHS  = (float*)(ws + WS_CHS);
  float* HST  = (float*)(ws + WS_HST);
  u16*  YBF   = (u16*)(ws + WS_YBF);

  dim3 tb(32, 8);
  // weight prep
  hipMemsetAsync(WBC, 0, 128 * 2048 * 2, stream);
  transpose_cvt<<<dim3(4096 / 32, 1024 / 32), tb, 0, stream>>>(w_in,  WINT, 1024, 4096);
  transpose_cvt<<<dim3(1024 / 32, 2048 / 32), tb, 0, stream>>>(w_out, WOUTT, 2048, 1024);
  transpose_cvt<<<dim3(2, 64), tb, 0, stream>>>(w_dti, WBC,               2048, 64);
  transpose_cvt<<<dim3(1, 64), tb, 0, stream>>>(w_b,   WBC + 64 * 2048,   2048, 16);
  transpose_cvt<<<dim3(1, 64), tb, 0, stream>>>(w_c,   WBC + 80 * 2048,   2048, 16);
  transpose_cvt<<<dim3(64, 2), tb, 0, stream>>>(w_dto, WDT2T,             64, 2048);
  bias_combine<<<8, 256, 0, stream>>>(b_dto, dtbias, DTB2);

  // norm + in_proj: 256^2 tiles, grid 16x16=256, XCD rect 4 rows x 8 cols
  rmsnorm_k<<<NTOK, 256, 0, stream>>>(x, nscale, XN);
  gemm_db<256, 256, 2, 4, 0><<<256, 512, 0, stream>>>(
      XN, WINT, b_in, nullptr, UZ, NTOK, 4096, 1024, 4, 8);

  // conv + silu (read-once, bf16 in/out)
  conv_silu_seq<<<NBATCH * 32 * 8, 256, 0, stream>>>(UZ, convk, convb, U);

  // dt1 / B / C: split-K=8 over K=2048, then reduce+split
  gemm_bt<1, 128><<<dim3(1, NTOK / 128, 8), 256, 0, stream>>>(
      U, WBC, nullptr, nullptr, DTBC, NTOK, 128, 2048, 256);
  prep_dtbc<<<(NTOK * 96 + 255) / 256, 256, 0, stream>>>(DTBC, b_dti, b_b, b_c, DT1, BMAT, CMAT);

  // dt2 + softplus + clip -> bf16 DT
  gemm_bt<2, 128><<<dim3(2048 / 128, NTOK / 128, 1), 256, 0, stream>>>(
      DT1, WDT2T, DTB2, nullptr, DT, NTOK, 2048, 64, 64);

  // chunked selective scan (state-split 2, 16 waves/CU)
  scan_pass1<<<NBATCH * NCH * 16, 256, 0, stream>>>(DT, U, BMAT, alog, CHP, CHS);
  scan_pass2<<<NBATCH * 128, 256, 0, stream>>>(CHP, CHS, HST);
  scan_pass3<<<NBATCH * NCH * 16, 256, 0, stream>>>(DT, U, BMAT, CMAT, alog, dvec, UZ, HST, YBF);

  // out_proj + residual: 128^2 tiles, grid 32x8=256, XCD rect 4 rows x 8 cols
  gemm_db<128, 128, 2, 2, 3><<<256, 256, 0, stream>>>(
      YBF, WOUTT, b_out, x, out, NTOK, 1024, 2048, 4, 8);
}

// Round 5
// 260.425 us; speedup vs baseline: 1.0607x; 1.0607x over previous
//
#include <hip/hip_runtime.h>
#include <cstdint>
#include <cstddef>

typedef unsigned short u16;
typedef __bf16 bf16x8 __attribute__((ext_vector_type(8)));
typedef float f32x4 __attribute__((ext_vector_type(4)));
typedef u16 u16x4 __attribute__((ext_vector_type(4)));

#define DMODEL 1024
#define DINNER 2048
#define NBATCH 2
#define LSEQ   2048
#define NTOK   4096   // NBATCH * LSEQ
#define NSTATE 16
#define NCH    64     // scan chunks
#define TCH    32     // timesteps per chunk (NCH*TCH == LSEQ)

__device__ __forceinline__ u16 f2b(float f) {
  union { float f; unsigned u; } a; a.f = f;
  unsigned r = a.u + 0x7fffu + ((a.u >> 16) & 1u);
  return (u16)(r >> 16);
}
__device__ __forceinline__ float b2f(u16 h) {
  union { unsigned u; float f; } a; a.u = ((unsigned)h) << 16;
  return a.f;
}

__device__ __forceinline__ void gload_lds16(const u16* g, __bf16* l) {
  __builtin_amdgcn_global_load_lds(
      (const __attribute__((address_space(1))) unsigned int*)g,
      (__attribute__((address_space(3))) unsigned int*)l, 16, 0, 0);
}

// ---------------- transpose + f32->bf16 convert: dst[c*R + r] = src[r*C + c]
__global__ __launch_bounds__(256)
void transpose_cvt(const float* __restrict__ src, u16* __restrict__ dst, int R, int C) {
  __shared__ float tile[32][33];
  int c0 = blockIdx.x * 32, r0 = blockIdx.y * 32;
  int x = threadIdx.x, y = threadIdx.y;            // blockDim (32,8)
  #pragma unroll
  for (int yy = y; yy < 32; yy += 8)
    if (r0 + yy < R && c0 + x < C) tile[yy][x] = src[(size_t)(r0 + yy) * C + c0 + x];
  __syncthreads();
  #pragma unroll
  for (int yy = y; yy < 32; yy += 8)
    if (c0 + yy < C && r0 + x < R) dst[(size_t)(c0 + yy) * R + r0 + x] = f2b(tile[x][yy]);
}

// ---------------- RMSNorm -> bf16 (one block per row of 1024)
__global__ __launch_bounds__(256)
void rmsnorm_k(const float* __restrict__ x, const float* __restrict__ scale, u16* __restrict__ xn) {
  int row = blockIdx.x;
  const float4* xp = (const float4*)(x + (size_t)row * DMODEL);
  float4 v = xp[threadIdx.x];
  float ss = v.x * v.x + v.y * v.y + v.z * v.z + v.w * v.w;
  #pragma unroll
  for (int o = 32; o; o >>= 1) ss += __shfl_down(ss, o);
  __shared__ float wsum[4];
  if ((threadIdx.x & 63) == 0) wsum[threadIdx.x >> 6] = ss;
  __syncthreads();
  float tot = wsum[0] + wsum[1] + wsum[2] + wsum[3];
  float r = rsqrtf(tot * (1.0f / DMODEL) + 1e-6f);
  float4 sc = ((const float4*)scale)[threadIdx.x];
  u16x4 o4;
  o4[0] = f2b(v.x * r * sc.x); o4[1] = f2b(v.y * r * sc.y);
  o4[2] = f2b(v.z * r * sc.z); o4[3] = f2b(v.w * r * sc.w);
  *(u16x4*)(xn + (size_t)row * DMODEL + threadIdx.x * 4) = o4;
}

// ======== double-buffered counted-vmcnt MFMA GEMM with XCD-rect L2 blocking ========
// out[M][N] = A[M][K]*Bt[N][K]. Grid must be 8*RM*RN blocks; XCD x runs an RMxRN
// rectangle of tiles -> row/col panels L2-resident, L3 re-fetch cut ~5x.
// EPI: 0 = +bias -> bf16, 3 = +bias+residual -> f32
template <int BM, int BN, int NWM, int NWN, int EPI>
__global__ __launch_bounds__(NWM * NWN * 64, 1)
void gemm_db(const u16* __restrict__ A, const u16* __restrict__ Bt,
             const float* __restrict__ bias, const float* __restrict__ res,
             void* __restrict__ outv, int M, int N, int K, int RM, int RN) {
  constexpr int NTHR = NWM * NWN * 64;
  constexpr int WMW = BM / NWM;
  constexpr int WNW = BN / NWN;
  constexpr int MF = WMW / 16;
  constexpr int NF = WNW / 16;
  constexpr int LPT = (BM + BN) * 8 / NTHR;   // global_load_lds per thread per tile
  __shared__ __bf16 lds[2][(BM + BN) * 64];
  const int tid = threadIdx.x;
  const int lane = tid & 63;
  const int wave = tid >> 6;
  const int wr = wave / NWN, wc = wave % NWN;

  const int GM = M / BM;
  const int bid = blockIdx.x;
  const int xcd = bid & 7;
  const int l = bid >> 3;
  const int rgm = GM / RM;
  const int rr = xcd % rgm, rc = xcd / rgm;
  const size_t m0 = (size_t)(rr * RM + (l % RM)) * BM;
  const size_t n0 = (size_t)(rc * RN + (l / RM)) * BN;
  const int NT = K >> 6;

#define STAGE_DB(bufi, k0)                                                     \
  { _Pragma("unroll")                                                          \
    for (int ss = 0; ss < BM * 8 / NTHR; ss++) {                               \
      int g = tid + ss * NTHR;                                                 \
      int row = g >> 3;                                                        \
      int kk = ((g & 7) * 8) ^ ((row & 7) << 3);                               \
      gload_lds16(A + (m0 + row) * K + (k0) + kk, &lds[bufi][g * 8]);          \
    }                                                                          \
    _Pragma("unroll")                                                          \
    for (int ss = 0; ss < BN * 8 / NTHR; ss++) {                               \
      int g = tid + ss * NTHR;                                                 \
      int row = g >> 3;                                                        \
      int kk = ((g & 7) * 8) ^ ((row & 7) << 3);                               \
      gload_lds16(Bt + (n0 + row) * K + (k0) + kk,                             \
                  &lds[bufi][BM * 64 + g * 8]);                                \
    } }

  f32x4 acc[MF][NF] = {};
  STAGE_DB(0, 0)
  STAGE_DB(1, 64)

  const int rsw = (lane & 7) << 3;
  const int arow0 = wr * WMW + (lane & 15);
  const int brow0 = wc * WNW + (lane & 15);
  const int kgrp = (lane >> 4) * 8;

  for (int t = 0; t < NT; t++) {
    const int cur = t & 1;
    if (t == NT - 1) asm volatile("s_waitcnt vmcnt(0)" ::: "memory");
    else             asm volatile("s_waitcnt vmcnt(%0)" :: "n"(LPT) : "memory");
    __builtin_amdgcn_s_barrier();
    asm volatile("" ::: "memory");
    const __bf16* As_ = &lds[cur][0];
    const __bf16* Bs_ = &lds[cur][BM * 64];
    #pragma unroll
    for (int qr = 0; qr < MF / 4; qr++) {
      #pragma unroll
      for (int qc = 0; qc < NF / 2; qc++) {
        bf16x8 af[2][4], bfv[2][2];
        #pragma unroll
        for (int ks = 0; ks < 2; ks++) {
          const int kk = (ks * 32 + kgrp) ^ rsw;
          #pragma unroll
          for (int i = 0; i < 4; i++)
            af[ks][i] = *(const bf16x8*)(As_ + (size_t)(arow0 + (qr * 4 + i) * 16) * 64 + kk);
          #pragma unroll
          for (int j = 0; j < 2; j++)
            bfv[ks][j] = *(const bf16x8*)(Bs_ + (size_t)(brow0 + (qc * 2 + j) * 16) * 64 + kk);
        }
        __builtin_amdgcn_s_setprio(1);
        #pragma unroll
        for (int ks = 0; ks < 2; ks++)
          #pragma unroll
          for (int i = 0; i < 4; i++)
            #pragma unroll
            for (int j = 0; j < 2; j++)
              acc[qr * 4 + i][qc * 2 + j] = __builtin_amdgcn_mfma_f32_16x16x32_bf16(
                  af[ks][i], bfv[ks][j], acc[qr * 4 + i][qc * 2 + j], 0, 0, 0);
        __builtin_amdgcn_s_setprio(0);
        __builtin_amdgcn_sched_barrier(0);
      }
    }
    __builtin_amdgcn_s_barrier();
    asm volatile("" ::: "memory");
    if (t + 2 < NT) { STAGE_DB(cur, (t + 2) * 64) }
  }

  const int cr = (lane >> 4) << 2;
  const int cc = lane & 15;
  #pragma unroll
  for (int fr = 0; fr < MF; fr++) {
    #pragma unroll
    for (int fc = 0; fc < NF; fc++) {
      const size_t col = n0 + wc * WNW + fc * 16 + cc;
      const float bv = bias[col];
      #pragma unroll
      for (int r = 0; r < 4; r++) {
        const size_t row = m0 + wr * WMW + fr * 16 + cr + r;
        if constexpr (EPI == 0) {
          ((u16*)outv)[row * N + col] = f2b(acc[fr][fc][r] + bv);
        } else {
          ((float*)outv)[row * N + col] = acc[fr][fc][r] + bv + res[row * N + col];
        }
      }
    }
  }
#undef STAGE_DB
}

// ---------------- padded reg-staged 2-phase GEMM for small shapes
// EPI: 1 = plain -> f32 partial (blockIdx.z offset), 2 = softplus+clip(+bias) -> bf16
template <int EPI, int BN>
__global__ __launch_bounds__(256)
void gemm_bt(const u16* __restrict__ A, const u16* __restrict__ Bt,
             const float* __restrict__ bias, const float* __restrict__ res,
             void* __restrict__ outv, int M, int N, int K, int ksplit) {
  constexpr int WN = BN / 2;
  constexpr int JN = WN / 16;
  __shared__ __bf16 As[128][72];
  __shared__ __bf16 Bs[BN][72];
  const int tid = threadIdx.x;
  const int m0 = blockIdx.y * 128;
  const int n0 = blockIdx.x * BN;
  const int wave = tid >> 6, lane = tid & 63;
  const int wm = (wave >> 1) * 64, wn = (wave & 1) * WN;
  const int sr = tid >> 3;
  const int sc = (tid & 7) * 8;
  const int kbeg = blockIdx.z * ksplit, kend = kbeg + ksplit;
  f32x4 acc[4][JN] = {};
  for (int k0 = kbeg; k0 < kend; k0 += 64) {
    __syncthreads();
    #pragma unroll
    for (int r = 0; r < 128; r += 32)
      *(bf16x8*)&As[sr + r][sc] = *(const bf16x8*)(A + (size_t)(m0 + sr + r) * K + k0 + sc);
    #pragma unroll
    for (int r = 0; r < BN; r += 32)
      *(bf16x8*)&Bs[sr + r][sc] = *(const bf16x8*)(Bt + (size_t)(n0 + sr + r) * K + k0 + sc);
    __syncthreads();
    #pragma unroll
    for (int ks = 0; ks < 64; ks += 32) {
      const int kr = ks + ((lane >> 4) << 3);
      bf16x8 af[4], bfr[JN];
      #pragma unroll
      for (int i = 0; i < 4; i++) af[i]  = *(const bf16x8*)&As[wm + (lane & 15) + i * 16][kr];
      #pragma unroll
      for (int j = 0; j < JN; j++) bfr[j] = *(const bf16x8*)&Bs[wn + (lane & 15) + j * 16][kr];
      #pragma unroll
      for (int i = 0; i < 4; i++)
        #pragma unroll
        for (int j = 0; j < JN; j++)
          acc[i][j] = __builtin_amdgcn_mfma_f32_16x16x32_bf16(af[i], bfr[j], acc[i][j], 0, 0, 0);
    }
  }
  const int cr = (lane >> 4) << 2;
  const int cc = lane & 15;
  #pragma unroll
  for (int i = 0; i < 4; i++) {
    #pragma unroll
    for (int j = 0; j < JN; j++) {
      const int col = n0 + wn + j * 16 + cc;
      #pragma unroll
      for (int r = 0; r < 4; r++) {
        const int row = m0 + wm + i * 16 + cr + r;
        float v = acc[i][j][r];
        if constexpr (EPI == 1) {
          ((float*)outv)[(size_t)blockIdx.z * M * N + (size_t)row * N + col] = v;
        } else {
          v += bias[col];
          v = (v > 20.0f) ? v : log1pf(__expf(v));
          v = fminf(fmaxf(v, 0.001f), 0.1f);
          ((u16*)outv)[(size_t)row * N + col] = f2b(v);
        }
      }
    }
  }
}

// ---------------- causal depthwise conv(4) + bias + SiLU -> bf16 (read-once)
__global__ __launch_bounds__(256)
void conv_silu_seq(const u16* __restrict__ uz, const float* __restrict__ ck,
                   const float* __restrict__ cb, u16* __restrict__ u) {
  int d  = (blockIdx.x & 7) * 256 + threadIdx.x;
  int lc = (blockIdx.x >> 3) & 31;
  int b  = blockIdx.x >> 8;
  const float w0 = ck[d], w1 = ck[DINNER + d], w2 = ck[2 * DINNER + d], w3 = ck[3 * DINNER + d];
  const float bias = cb[d];
  const int t0 = lc * 64;
  float x0 = 0.f, x1 = 0.f, x2 = 0.f;
  #pragma unroll
  for (int j = -3; j < 0; j++) {
    int t = t0 + j;
    float v = (t >= 0) ? b2f(uz[((size_t)(b * LSEQ + t)) * (2 * DINNER) + d]) : 0.f;
    x0 = x1; x1 = x2; x2 = v;
  }
  for (int i = 0; i < 64; i++) {
    int t = t0 + i;
    float x3 = b2f(uz[((size_t)(b * LSEQ + t)) * (2 * DINNER) + d]);
    float acc = bias + w0 * x0 + w1 * x1 + w2 * x2 + w3 * x3;
    float sv = acc / (1.0f + __expf(-acc));
    u[((size_t)(b * LSEQ + t)) * DINNER + d] = f2b(sv);
    x0 = x1; x1 = x2; x2 = x3;
  }
}

// ---------------- reduce split-K partials + split dtbc
__global__ __launch_bounds__(256)
void prep_dtbc(const float* __restrict__ dtbc, const float* __restrict__ dtin_b,
               const float* __restrict__ bb, const float* __restrict__ cbias,
               u16* __restrict__ dt1, float* __restrict__ Bm, float* __restrict__ Cm) {
  int idx = blockIdx.x * 256 + threadIdx.x;
  if (idx >= NTOK * 96) return;
  int row = idx / 96, col = idx - row * 96;
  float v = 0.f;
  #pragma unroll
  for (int z = 0; z < 8; z++)
    v += dtbc[(size_t)z * NTOK * 128 + (size_t)row * 128 + col];
  if (col < 64)       dt1[(size_t)row * 64 + col] = f2b(v + dtin_b[col]);
  else if (col < 80)  Bm[(size_t)row * NSTATE + col - 64] = tanhf(v + bb[col - 64]);
  else                Cm[(size_t)row * NSTATE + col - 80] = tanhf(v + cbias[col - 80]);
}

__global__ void bias_combine(const float* a, const float* b, float* o) {
  int i = blockIdx.x * 256 + threadIdx.x;
  if (i < DINNER) o[i] = a[i] + b[i];
}

// ======== chunked selective scan: 1 thread per d, 16 states, NCH=64 chunks ========
// chP/chS layout: [b][ch][d][s]
__global__ __launch_bounds__(256)
void scan_pass1(const u16* __restrict__ dt, const u16* __restrict__ u,
                const float* __restrict__ Bm, const float* __restrict__ alog,
                float* __restrict__ chP, float* __restrict__ chS) {
  const int d  = (blockIdx.x & 7) * 256 + threadIdx.x;
  const int ch = (blockIdx.x >> 3) & (NCH - 1);
  const int b  = blockIdx.x >> 9;
  float A[NSTATE];
  #pragma unroll
  for (int s = 0; s < NSTATE; s++) A[s] = -__expf(alog[(size_t)d * NSTATE + s]);
  float h[NSTATE], P[NSTATE];
  #pragma unroll
  for (int s = 0; s < NSTATE; s++) { h[s] = 0.0f; P[s] = 1.0f; }
  const int t0 = ch * TCH;
  for (int i = 0; i < TCH; i++) {
    const size_t tok = (size_t)b * LSEQ + t0 + i;
    float dtv = b2f(dt[tok * DINNER + d]);
    float uv  = b2f(u[tok * DINNER + d]);
    float dtu = dtv * uv;
    const float* bp = Bm + tok * NSTATE;
    #pragma unroll
    for (int s = 0; s < NSTATE; s++) {
      float da = __expf(dtv * A[s]);
      P[s] *= da;
      h[s] = da * h[s] + dtu * bp[s];
    }
  }
  size_t base = (((size_t)b * NCH + ch) * DINNER + d) * NSTATE;
  #pragma unroll
  for (int s = 0; s < NSTATE; s++) { chP[base + s] = P[s]; chS[base + s] = h[s]; }
}

// pass2: stitch chunks; hst MAY alias chS (read-before-write)
__global__ __launch_bounds__(256)
void scan_pass2(const float* __restrict__ chP, const float* __restrict__ chS,
                float* __restrict__ hst) {
  const int b   = blockIdx.x >> 7;                        // 128 blocks per batch
  const int off = (blockIdx.x & 127) * 256 + threadIdx.x; // d*16+s
  float h = 0.f;
  const size_t stride = (size_t)DINNER * NSTATE;
  size_t base = (size_t)b * NCH * stride + off;
  for (int c = 0; c < NCH; c++) {
    size_t a = base + (size_t)c * stride;
    float P = chP[a], S = chS[a];
    hst[a] = h;
    h = P * h + S;
  }
}

// pass3: replay + y = (sum h*c + u*d) * silu(z) -> bf16
__global__ __launch_bounds__(256)
void scan_pass3(const u16* __restrict__ dt, const u16* __restrict__ u,
                const float* __restrict__ Bm, const float* __restrict__ Cm,
                const float* __restrict__ alog, const float* __restrict__ dvec,
                const u16* __restrict__ uz, const float* __restrict__ hst,
                u16* __restrict__ y) {
  const int d  = (blockIdx.x & 7) * 256 + threadIdx.x;
  const int ch = (blockIdx.x >> 3) & (NCH - 1);
  const int b  = blockIdx.x >> 9;
  float A[NSTATE];
  #pragma unroll
  for (int s = 0; s < NSTATE; s++) A[s] = -__expf(alog[(size_t)d * NSTATE + s]);
  float h[NSTATE];
  const size_t hbase = (((size_t)b * NCH + ch) * DINNER + d) * NSTATE;
  #pragma unroll
  for (int s = 0; s < NSTATE; s++) h[s] = hst[hbase + s];
  const float dval = dvec[d];
  const int t0 = ch * TCH;
  for (int i = 0; i < TCH; i++) {
    const size_t tok = (size_t)b * LSEQ + t0 + i;
    float dtv = b2f(dt[tok * DINNER + d]);
    float uv  = b2f(u[tok * DINNER + d]);
    float dtu = dtv * uv;
    const float* bp = Bm + tok * NSTATE;
    const float* cp = Cm + tok * NSTATE;
    float yv = 0.0f;
    #pragma unroll
    for (int s = 0; s < NSTATE; s++) {
      float da = __expf(dtv * A[s]);
      h[s] = da * h[s] + dtu * bp[s];
      yv += h[s] * cp[s];
    }
    yv += uv * dval;
    float z = b2f(uz[tok * (2 * DINNER) + DINNER + d]);
    float g = z / (1.0f + __expf(-z));
    y[tok * DINNER + d] = f2b(yv * g);
  }
}

// ---------------- workspace layout (bytes) — with aliases
// CHP aliases XN+WINT (dead after in_proj). HST == CHS (pass2 reads-then-writes).
#define WS_XN     ((size_t)0)                  // 4096*1024*2 = 8388608
#define WS_WINT   (WS_XN     + 8388608)        // 8388608
#define WS_CHP    ((size_t)0)                  // 2*64*2048*16*4 = 16777216 (alias)
#define WS_WOUTT  (WS_WINT   + 8388608)        // 1024*2048*2 = 4194304
#define WS_WBC    (WS_WOUTT  + 4194304)        // 128*2048*2 = 524288
#define WS_WDT2T  (WS_WBC    + 524288)         // 2048*64*2 = 262144
#define WS_DT1    (WS_WDT2T  + 262144)         // 4096*64*2 = 524288
#define WS_DTB2   (WS_DT1    + 524288)         // 8192
#define WS_BMAT   (WS_DTB2   + 8192)           // 4096*16*4 = 262144
#define WS_CMAT   (WS_BMAT   + 262144)         // 262144
#define WS_UZ     (WS_CMAT   + 262144)         // 4096*4096*2 = 33554432
#define WS_U      (WS_UZ     + 33554432)       // 4096*2048*2 = 16777216
#define WS_DTBC   (WS_U      + 16777216)       // 8*4096*128*4 = 16777216
#define WS_DT     (WS_DTBC   + 16777216)       // 4096*2048*2 = 16777216
#define WS_CHS    (WS_DT     + 16777216)       // 16777216 (== HST)
#define WS_YBF    (WS_CHS    + 16777216)       // 4096*2048*2 = 16777216

extern "C" void kernel_launch(void* const* d_in, const int* in_sizes, int n_in,
                              void* d_out, int out_size, void* d_ws, size_t ws_size,
                              hipStream_t stream) {
  const float* x      = (const float*)d_in[0];
  const float* nscale = (const float*)d_in[1];
  const float* w_in   = (const float*)d_in[2];
  const float* b_in   = (const float*)d_in[3];
  const float* w_out  = (const float*)d_in[4];
  const float* b_out  = (const float*)d_in[5];
  const float* w_dti  = (const float*)d_in[6];
  const float* b_dti  = (const float*)d_in[7];
  const float* w_dto  = (const float*)d_in[8];
  const float* b_dto  = (const float*)d_in[9];
  const float* w_b    = (const float*)d_in[10];
  const float* b_b    = (const float*)d_in[11];
  const float* w_c    = (const float*)d_in[12];
  const float* b_c    = (const float*)d_in[13];
  const float* convk  = (const float*)d_in[14];
  const float* convb  = (const float*)d_in[15];
  const float* alog   = (const float*)d_in[16];
  const float* dvec   = (const float*)d_in[17];
  const float* dtbias = (const float*)d_in[18];
  float* out = (float*)d_out;
  char* ws = (char*)d_ws;

  u16*  XN    = (u16*)(ws + WS_XN);
  u16*  WINT  = (u16*)(ws + WS_WINT);
  u16*  WOUTT = (u16*)(ws + WS_WOUTT);
  u16*  WBC   = (u16*)(ws + WS_WBC);
  u16*  WDT2T = (u16*)(ws + WS_WDT2T);
  u16*  DT1   = (u16*)(ws + WS_DT1);
  float* DTB2 = (float*)(ws + WS_DTB2);
  float* BMAT = (float*)(ws + WS_BMAT);
  float* CMAT = (float*)(ws + WS_CMAT);
  u16*  UZ    = (u16*)(ws + WS_UZ);
  u16*  U     = (u16*)(ws + WS_U);
  float* DTBC = (float*)(ws + WS_DTBC);
  u16*  DT    = (u16*)(ws + WS_DT);
  float* CHP  = (float*)(ws + WS_CHP);
  float* CHS  = (float*)(ws + WS_CHS);
  float* HST  = (float*)(ws + WS_CHS);   // alias: pass2 reads chS then writes hst
  u16*  YBF   = (u16*)(ws + WS_YBF);

  dim3 tb(32, 8);
  // weight prep
  hipMemsetAsync(WBC, 0, 128 * 2048 * 2, stream);
  transpose_cvt<<<dim3(4096 / 32, 1024 / 32), tb, 0, stream>>>(w_in,  WINT, 1024, 4096);
  transpose_cvt<<<dim3(1024 / 32, 2048 / 32), tb, 0, stream>>>(w_out, WOUTT, 2048, 1024);
  transpose_cvt<<<dim3(2, 64), tb, 0, stream>>>(w_dti, WBC,               2048, 64);
  transpose_cvt<<<dim3(1, 64), tb, 0, stream>>>(w_b,   WBC + 64 * 2048,   2048, 16);
  transpose_cvt<<<dim3(1, 64), tb, 0, stream>>>(w_c,   WBC + 80 * 2048,   2048, 16);
  transpose_cvt<<<dim3(64, 2), tb, 0, stream>>>(w_dto, WDT2T,             64, 2048);
  bias_combine<<<8, 256, 0, stream>>>(b_dto, dtbias, DTB2);

  // norm + in_proj: 256^2 tiles, grid 16x16=256, XCD rect 4 rows x 8 cols
  rmsnorm_k<<<NTOK, 256, 0, stream>>>(x, nscale, XN);
  gemm_db<256, 256, 2, 4, 0><<<256, 512, 0, stream>>>(
      XN, WINT, b_in, nullptr, UZ, NTOK, 4096, 1024, 4, 8);

  // conv + silu (read-once, bf16 in/out)
  conv_silu_seq<<<NBATCH * 32 * 8, 256, 0, stream>>>(UZ, convk, convb, U);

  // dt1 / B / C: split-K=8 over K=2048, then reduce+split
  gemm_bt<1, 128><<<dim3(1, NTOK / 128, 8), 256, 0, stream>>>(
      U, WBC, nullptr, nullptr, DTBC, NTOK, 128, 2048, 256);
  prep_dtbc<<<(NTOK * 96 + 255) / 256, 256, 0, stream>>>(DTBC, b_dti, b_b, b_c, DT1, BMAT, CMAT);

  // dt2 + softplus + clip -> bf16 DT
  gemm_bt<2, 128><<<dim3(2048 / 128, NTOK / 128, 1), 256, 0, stream>>>(
      DT1, WDT2T, DTB2, nullptr, DT, NTOK, 2048, 64, 64);

  // chunked selective scan (NCH=64 chunks -> 1024 blocks/pass)
  scan_pass1<<<NBATCH * NCH * 8, 256, 0, stream>>>(DT, U, BMAT, alog, CHP, CHS);
  scan_pass2<<<NBATCH * 128, 256, 0, stream>>>(CHP, CHS, HST);
  scan_pass3<<<NBATCH * NCH * 8, 256, 0, stream>>>(DT, U, BMAT, CMAT, alog, dvec, UZ, HST, YBF);

  // out_proj + residual: 128^2 tiles, grid 32x8=256, XCD rect 4 rows x 8 cols
  gemm_db<128, 128, 2, 2, 3><<<256, 256, 0, stream>>>(
      YBF, WOUTT, b_out, x, out, NTOK, 1024, 2048, 4, 8);
}